// Round 8
// baseline (205.348 us; speedup 1.0000x reference)
//
#include <hip/hip_runtime.h>

// B=8, H=8, L=2048, D=64, num_delays=16
static constexpr int LSEQ = 2048;
static constexpr int NB   = 8;
static constexpr int NH   = 8;
static constexpr int ND   = 64;
static constexpr int NDEL = 16;

// ws layout (same 8.4 MB proven-safe envelope, same w/delay offsets):
//   Pc    : float2[128 part][8 b][1024]  at 0      (exactly 8 MiB)
//           compact partial spectra: slot j in [1,1024) holds freq j;
//           slot 0 packs (Re S[0], Re S[1024]) — both freqs are purely real.
//           After reduce_S, part 0 holds the reduced compact spectrum.
//   w     : float [8][16]               at 8388608
//   delay : int   [8][16]               at 8389120
static constexpr size_t WS_P_OFF     = 0;
static constexpr size_t WS_W_OFF     = 8388608;
static constexpr size_t WS_DELAY_OFF = 8389120;

// LDS bank swizzle on float2 index: fold bits 4..6 into bits 1..3.
// Touches only bits 1..3 — band bits (8..10) and 32-group bits (5..7) are
// preserved, which is what makes the intra-wave barrier elision legal.
__device__ __forceinline__ int SWZ(int x) { return x ^ (((x >> 4) & 7) << 1); }

// digit-reversed position of frequency f (radices 8,8,8,4 DIF) and inverse
__device__ __forceinline__ int pof(int f) {
    return ((f & 7) << 8) | (((f >> 3) & 7) << 5) | (((f >> 6) & 7) << 2) | (f >> 9);
}
__device__ __forceinline__ int fofp(int p) {
    return (p >> 8) | (((p >> 5) & 7) << 3) | (((p >> 2) & 7) << 6) | ((p & 3) << 9);
}

#define CMUL(ar, ai, br, bi) make_float2((ar)*(br) - (ai)*(bi), (ar)*(bi) + (ai)*(br))

// 8-pt DIF DFT in regs; x[0..7] in, X[0..7] (natural freq order) out.
__device__ __forceinline__ void dft8(const float2 x[8], float2 X[8]) {
    const float RH = 0.70710678118654752440f;
    float2 a0 = make_float2(x[0].x + x[4].x, x[0].y + x[4].y);
    float2 a1 = make_float2(x[1].x + x[5].x, x[1].y + x[5].y);
    float2 a2 = make_float2(x[2].x + x[6].x, x[2].y + x[6].y);
    float2 a3 = make_float2(x[3].x + x[7].x, x[3].y + x[7].y);
    float2 b0 = make_float2(x[0].x - x[4].x, x[0].y - x[4].y);
    float  t1r = x[1].x - x[5].x, t1i = x[1].y - x[5].y;
    float2 b1 = make_float2(RH * (t1r + t1i), RH * (t1i - t1r));       // * w8^1
    float  t2r = x[2].x - x[6].x, t2i = x[2].y - x[6].y;
    float2 b2 = make_float2(t2i, -t2r);                                // * -i
    float  t3r = x[3].x - x[7].x, t3i = x[3].y - x[7].y;
    float2 b3 = make_float2(RH * (t3i - t3r), -RH * (t3r + t3i));      // * w8^3
    float2 c0 = make_float2(a0.x + a2.x, a0.y + a2.y);
    float2 d0 = make_float2(a0.x - a2.x, a0.y - a2.y);
    float2 c1 = make_float2(a1.x + a3.x, a1.y + a3.y);
    float2 d1 = make_float2(a1.y - a3.y, -(a1.x - a3.x));              // * -i
    X[0] = make_float2(c0.x + c1.x, c0.y + c1.y);
    X[4] = make_float2(c0.x - c1.x, c0.y - c1.y);
    X[2] = make_float2(d0.x + d1.x, d0.y + d1.y);
    X[6] = make_float2(d0.x - d1.x, d0.y - d1.y);
    float2 e0 = make_float2(b0.x + b2.x, b0.y + b2.y);
    float2 f0 = make_float2(b0.x - b2.x, b0.y - b2.y);
    float2 e1 = make_float2(b1.x + b3.x, b1.y + b3.y);
    float2 f1 = make_float2(b1.y - b3.y, -(b1.x - b3.x));              // * -i
    X[1] = make_float2(e0.x + e1.x, e0.y + e1.y);
    X[5] = make_float2(e0.x - e1.x, e0.y - e1.y);
    X[3] = make_float2(f0.x + f1.x, f0.y + f1.y);
    X[7] = make_float2(f0.x - f1.x, f0.y - f1.y);
}

// 4-pt DFT: X[m] = sum_j x[j] (-i)^{jm}
__device__ __forceinline__ void dft4(const float2 x[4], float2 X[4]) {
    float2 s0 = make_float2(x[0].x + x[2].x, x[0].y + x[2].y);
    float2 s1 = make_float2(x[1].x + x[3].x, x[1].y + x[3].y);
    float2 d0 = make_float2(x[0].x - x[2].x, x[0].y - x[2].y);
    float2 d1 = make_float2(x[1].y - x[3].y, -(x[1].x - x[3].x));      // * -i
    X[0] = make_float2(s0.x + s1.x, s0.y + s1.y);
    X[2] = make_float2(s0.x - s1.x, s0.y - s1.y);
    X[1] = make_float2(d0.x + d1.x, d0.y + d1.y);
    X[3] = make_float2(d0.x - d1.x, d0.y - d1.y);
}

// in-place radix-8 stage with twiddle chain W on LDS plane zp
__device__ __forceinline__ void stageR8(float2* zp, const int adr[8], const float2 W[7]) {
    float2 X[8], Y[8];
    #pragma unroll
    for (int j = 0; j < 8; ++j) X[j] = zp[adr[j]];
    dft8(X, Y);
    #pragma unroll
    for (int m = 1; m < 8; ++m) Y[m] = CMUL(Y[m].x, Y[m].y, W[m-1].x, W[m-1].y);
    #pragma unroll
    for (int m = 0; m < 8; ++m) zp[adr[m]] = Y[m];
}

// final twiddle-free stage: two radix-4 on 8 consecutive; in-place
__device__ __forceinline__ void stageD_ip(float2* zp, const int adr[8]) {
    float2 xin[8], X[8];
    #pragma unroll
    for (int j = 0; j < 8; ++j) xin[j] = zp[adr[j]];
    dft4(&xin[0], &X[0]);
    dft4(&xin[4], &X[4]);
    #pragma unroll
    for (int m = 0; m < 8; ++m) zp[adr[m]] = X[m];
}

// ---------------------------------------------------------------------------
// Kernel A: 4-PLANE single-pass variant. All 4 d-channels of the block run
// concurrently on 4 LDS planes (64 KiB). Stage A scatters all 4 planes ->
// ONE barrier -> BCD per plane back-to-back (intra-wave region, proven in
// round 6: bands owned by 32-clusters ⊂ one wave; SWZ preserves band bits;
// planes are independent -> 4x the in-flight DS work per phase) -> ONE
// barrier -> product reads Zf AND mirrors from LDS (stage D wrote X back at
// adrD, so no X register arrays persist). Barriers/block: 5 -> 2.
// Theory: fft_corr is phase-latency-convoyed (VALUBusy 14-17%, HBM 8%);
// fewer, fatter phases attack exactly that.
// ---------------------------------------------------------------------------
__global__ __launch_bounds__(256, 2) void fft_corr(const float* __restrict__ q,
                                                   const float* __restrict__ k,
                                                   float2* __restrict__ Pc) {
    __shared__ float2 z[4][LSEQ];           // 64 KiB (swizzled planes)
    const int t    = threadIdx.x;
    const int bi   = blockIdx.x;            // 1024 = 8 xcd * 8 bh * 8 grp * 2 half
    const int xcd  = bi & 7;
    const int sl   = bi >> 3;               // 0..127
    const int bh   = xcd * 8 + (sl >> 4);   // 16 blocks of same bh share an XCD
    const int grp  = (sl >> 1) & 7;
    const int half = sl & 1;
    const int b    = bh >> 3;
    const int h    = bh & 7;
    const size_t base = (size_t)bh * LSEQ * ND + (size_t)(grp * 8 + half * 4);

    // twiddle power chains (per thread, shared by all channels)
    float2 WA[7], WB[7], WC[7];
    {
        float sn, cs;
        __sincosf(-6.28318530717958647692f * (float)t / 2048.f, &sn, &cs);
        WA[0] = make_float2(cs, sn);
        __sincosf(-6.28318530717958647692f * (float)(t & 31) / 256.f, &sn, &cs);
        WB[0] = make_float2(cs, sn);
        __sincosf(-6.28318530717958647692f * (float)(t & 3) / 32.f, &sn, &cs);
        WC[0] = make_float2(cs, sn);
        #pragma unroll
        for (int m = 1; m < 7; ++m) {
            WA[m] = CMUL(WA[m-1].x, WA[m-1].y, WA[0].x, WA[0].y);
            WB[m] = CMUL(WB[m-1].x, WB[m-1].y, WB[0].x, WB[0].y);
            WC[m] = CMUL(WC[m-1].x, WC[m-1].y, WC[0].x, WC[0].y);
        }
    }

    // owned product slots: cc in {0,1,4,5} -> f in [0,1024)
    int fS[4], pmS[4];
    #pragma unroll
    for (int s = 0; s < 4; ++s) {
        const int cc = (s < 2) ? s : s + 2;           // {0,1,4,5}
        const int f  = fofp(8 * t + cc);
        const int m  = (2048 - f) & 2047;
        fS[s]  = f;
        pmS[s] = SWZ(pof(m));
    }
    float aFr[4] = {0, 0, 0, 0}, aFi[4] = {0, 0, 0, 0};
    float aS = 0.f;                      // f=1024 special (thread 0)

    const int sbB   = (t >> 5) * 256 + (t & 31);
    const int baseC = (t >> 2) * 32 + (t & 3);
    int adrB[8], adrC[8], adrD[8];
    #pragma unroll
    for (int n = 0; n < 8; ++n) {
        adrB[n] = SWZ(sbB + 32 * n);
        adrC[n] = SWZ(baseC + 4 * n);
        adrD[n] = SWZ(8 * t + n);
    }

    float4 qa[8], ka[8];
    #pragma unroll
    for (int j = 0; j < 8; ++j) {
        const size_t r = base + (size_t)(t + 256 * j) * ND;
        qa[j] = *(const float4*)(q + r);
        ka[j] = *(const float4*)(k + r);
    }

    // ---- stage A for all 4 channels: radix-8 from regs, scatter to planes --
    #pragma unroll
    for (int c = 0; c < 4; ++c) {
        float2 X[8], Y[8];
        #pragma unroll
        for (int j = 0; j < 8; ++j)
            X[j] = make_float2((&qa[j].x)[c], (&ka[j].x)[c]);
        dft8(X, Y);
        #pragma unroll
        for (int m = 1; m < 8; ++m)
            Y[m] = CMUL(Y[m].x, Y[m].y, WA[m-1].x, WA[m-1].y);
        #pragma unroll
        for (int m = 0; m < 8; ++m) z[c][SWZ(m * 256 + t)] = Y[m];
    }
    __syncthreads();                 // A scatter complete (cross-wave)

    // ---- B,C,D on 4 independent planes — intra-wave region, no barriers ---
    #pragma unroll
    for (int c = 0; c < 4; ++c) {
        stageR8(z[c], adrB, WB);
        stageR8(z[c], adrC, WC);
        stageD_ip(z[c], adrD);
    }
    __syncthreads();                 // D writeback complete (mirror reads)

    // ---- product: acc Q[f] conj(K[f]) for 4 owned slots x 4 channels ------
    #pragma unroll
    for (int c = 0; c < 4; ++c) {
        #pragma unroll
        for (int s = 0; s < 4; ++s) {
            const int cc = (s < 2) ? s : s + 2;   // {0,1,4,5}
            const float2 Zf = z[c][adrD[cc]];     // stage-D wrote X[cc] here
            const float2 Zm = z[c][pmS[s]];
            const float qr = 0.5f * (Zf.x + Zm.x), qi = 0.5f * (Zf.y - Zm.y);
            const float kr = 0.5f * (Zf.y + Zm.y), ki = 0.5f * (Zm.x - Zf.x);
            aFr[s] += qr * kr + qi * ki;
            aFi[s] += qi * kr - qr * ki;
        }
    }
    if (t == 0) {
        #pragma unroll
        for (int c = 0; c < 4; ++c) {
            const float2 Z2 = z[c][2];            // SWZ(2)=2: slot of f=1024 pair
            aS += Z2.x * Z2.y;
        }
    }

    // compact store: Pc[part][b][f] = acc, f = fS[s] in [0,1024).
    // slot 0 packs (Re S[0], Re S[1024]); Im S[0] is mathematically 0.
    const int part = h * 16 + grp * 2 + half;        // 0..127
    float2* Pp = Pc + (size_t)part * (NB * 1024) + (size_t)b * 1024;
    #pragma unroll
    for (int s = 0; s < 4; ++s) Pp[fS[s]] = make_float2(aFr[s], aFi[s]);
    if (t == 0) Pp[0] = make_float2(aFr[0], aS);
}

// ---------------------------------------------------------------------------
// Reduce 128 compact partials IN-PLACE into part 0. 128 blocks; XCD-ALIGNED
// (round-6): all partials of batch b were written from XCD b; b = bi&7 keeps
// every read on the local XCD's L2.
// ---------------------------------------------------------------------------
__global__ __launch_bounds__(256) void reduce_S(float2* __restrict__ Pc) {
    __shared__ float2 acc[256];
    const int t     = threadIdx.x;
    const int bi    = blockIdx.x;                    // 128
    const int b     = bi & 7;                        // XCD-local batch
    const int seg   = bi >> 3;                       // 16 segments x 64 cols
    const int col   = b * 1024 + seg * 64 + (t & 63);
    const int slice = t >> 6;                        // 4 slices x 32 parts
    float ax = 0.f, ay = 0.f;
    #pragma unroll 8
    for (int pp = 0; pp < 32; ++pp) {
        const float2 v = Pc[(size_t)(slice * 32 + pp) * (NB * 1024) + col];
        ax += v.x; ay += v.y;
    }
    acc[t] = make_float2(ax, ay);
    __syncthreads();
    if (t < 64) {
        const float2 r0 = acc[t], r1 = acc[t + 64], r2 = acc[t + 128], r3 = acc[t + 192];
        Pc[col] = make_float2(r0.x + r1.x + r2.x + r3.x, r0.y + r1.y + r2.y + r3.y);
    }
}

// ---------------------------------------------------------------------------
// Kernel B: 256-thread verified FFT pipeline + intra-wave elision on B/C/D +
// per-wave register top-16 (round-7 verified; 6 barriers).
// ---------------------------------------------------------------------------
__global__ __launch_bounds__(256) void ifft_topk(const float2* __restrict__ S,
                                                 float* __restrict__ wout,
                                                 int* __restrict__ dout) {
    __shared__ float2 zz[LSEQ];          // 16 KiB work (swizzled in stages)
    __shared__ float  mc[LSEQ];          // 8 KiB, natural tau order
    __shared__ float  candv[4][NDEL];
    __shared__ int    candt[4][NDEL];
    const int b = blockIdx.x, t = threadIdx.x;

    float2 WA[7], WB[7], WC[7];
    {
        float sn, cs;
        __sincosf(-6.28318530717958647692f * (float)t / 2048.f, &sn, &cs);
        WA[0] = make_float2(cs, sn);
        __sincosf(-6.28318530717958647692f * (float)(t & 31) / 256.f, &sn, &cs);
        WB[0] = make_float2(cs, sn);
        __sincosf(-6.28318530717958647692f * (float)(t & 3) / 32.f, &sn, &cs);
        WC[0] = make_float2(cs, sn);
        #pragma unroll
        for (int m = 1; m < 7; ++m) {
            WA[m] = CMUL(WA[m-1].x, WA[m-1].y, WA[0].x, WA[0].y);
            WB[m] = CMUL(WB[m-1].x, WB[m-1].y, WB[0].x, WB[0].y);
            WC[m] = CMUL(WC[m-1].x, WC[m-1].y, WC[0].x, WC[0].y);
        }
    }
    const int sbB   = (t >> 5) * 256 + (t & 31);
    const int baseC = (t >> 2) * 32 + (t & 3);
    int adrB[8], adrC[8], adrD[8];
    #pragma unroll
    for (int n = 0; n < 8; ++n) {
        adrB[n] = SWZ(sbB + 32 * n);
        adrC[n] = SWZ(baseC + 4 * n);
        adrD[n] = SWZ(8 * t + n);
    }

    // load compact spectrum, reconstruct full digit-rev spectrum in zz:
    // freq j -> slot pof(j); freq 2048-j -> conj at slot pof(2048-j).
    #pragma unroll
    for (int u = 0; u < 4; ++u) {
        const int j = t + 256 * u;
        const float2 s = S[b * 1024 + j];
        if (j == 0) {
            zz[0] = make_float2(s.x, 0.f);            // pof(0)    = 0
            zz[2] = make_float2(s.y, 0.f);            // pof(1024) = 2
        } else {
            zz[pof(j)]        = s;
            zz[pof(2048 - j)] = make_float2(s.x, -s.y);
        }
    }
    __syncthreads();

    // gather stage-A operands: x[f] = conj(S[f]) at slot pof(f), f = t+256j
    float2 X[8], Y[8];
    #pragma unroll
    for (int j = 0; j < 8; ++j) {
        const float2 s = zz[pof(t + 256 * j)];
        X[j] = make_float2(s.x, -s.y);
    }
    __syncthreads();                     // all gathers done before scatter

    dft8(X, Y);
    #pragma unroll
    for (int m = 1; m < 8; ++m) Y[m] = CMUL(Y[m].x, Y[m].y, WA[m-1].x, WA[m-1].y);
    #pragma unroll
    for (int m = 0; m < 8; ++m) zz[SWZ(m * 256 + t)] = Y[m];
    __syncthreads();

    // B, C, D: intra-wave region (band t>>5 owned by the 32-cluster) — no
    // barriers (round-6 proof; same addressing, same SWZ).
    stageR8(zz, adrB, WB);
    stageR8(zz, adrC, WC);
    {
        float2 xin[8];
        #pragma unroll
        for (int j = 0; j < 8; ++j) xin[j] = zz[adrD[j]];
        dft4(&xin[0], &X[0]);
        dft4(&xin[4], &X[4]);
    }

    // mc[tau] = Re(out)/(L*H*D); slot 8t+cc holds tau = fofp(8t+cc)
    const float scale = 1.0f / ((float)LSEQ * (float)(NH * ND));
    #pragma unroll
    for (int cc = 0; cc < 8; ++cc) mc[fofp(8 * t + cc)] = X[cc].x * scale;
    __syncthreads();

    // ---- per-wave top-16 (wave w owns taus [512w, 512w+512), 8 regs/lane) --
    const int L = t & 63, wv = t >> 6;
    float v[8];
    #pragma unroll
    for (int u = 0; u < 8; ++u) v[u] = mc[512 * wv + 64 * u + L];

    for (int it = 0; it < NDEL; ++it) {
        // local argmax over 8 (ascending u = ascending tau -> ties keep smaller)
        float bv = v[0]; int bu = 0;
        #pragma unroll
        for (int u = 1; u < 8; ++u) if (v[u] > bv) { bv = v[u]; bu = u; }
        int bt_ = 512 * wv + 64 * bu + L;
        // wave-wide shfl reduce (ties -> smaller tau)
        #pragma unroll
        for (int off = 32; off; off >>= 1) {
            const float ov = __shfl_xor(bv, off);
            const int   ot = __shfl_xor(bt_, off);
            if (ov > bv || (ov == bv && ot < bt_)) { bv = ov; bt_ = ot; }
        }
        // owner lane clears the winner (static reg indexing)
        #pragma unroll
        for (int u = 0; u < 8; ++u)
            if (512 * wv + 64 * u + L == bt_) v[u] = -3e38f;
        if (L == 0) { candv[wv][it] = bv; candt[wv][it] = bt_; }
    }
    __syncthreads();

    // ---- merge 4 descending lists + softmax (thread 0) ----
    if (t == 0) {
        int hp[4] = {0, 0, 0, 0};
        float topv[NDEL]; int topi[NDEL];
        for (int it = 0; it < NDEL; ++it) {
            float bv = -3e38f; int bt_ = 1 << 30; int bw = 0;
            #pragma unroll
            for (int ww = 0; ww < 4; ++ww) {
                const float cv = candv[ww][hp[ww]];
                const int   ct = candt[ww][hp[ww]];
                if (cv > bv || (cv == bv && ct < bt_)) { bv = cv; bt_ = ct; bw = ww; }
            }
            topv[it] = bv; topi[it] = bt_; ++hp[bw];
        }
        const float m = topv[0];
        float e[NDEL], sum = 0.f;
        for (int i = 0; i < NDEL; ++i) { e[i] = __expf(topv[i] - m); sum += e[i]; }
        const float inv = 1.0f / sum;
        for (int i = 0; i < NDEL; ++i) {
            wout[b * NDEL + i] = e[i] * inv;
            dout[b * NDEL + i] = topi[i];
        }
    }
}

// ---------------------------------------------------------------------------
// Kernel C: out[b,h,t,d] = sum_k w[b,k] * v[b,h,(t+delay[b,k]) & 2047, d]
// XCD swizzle keeps each (b,h) v-slice L2-resident. out is write-once ->
// nontemporal stores (round-7 verified).
// ---------------------------------------------------------------------------
typedef float f4nt __attribute__((ext_vector_type(4)));

__global__ __launch_bounds__(256) void gather_out(const float* __restrict__ v,
                                                  const float* __restrict__ w,
                                                  const int* __restrict__ delay,
                                                  float* __restrict__ out) {
    const int bi  = blockIdx.x;          // 8192 = 64 bh * 128 tiles
    const int xcd = bi & 7;
    const int s   = bi >> 3;
    const int bh  = xcd * 8 + (s >> 7);
    const int bt  = s & 127;
    const int b   = bh >> 3;
    const int tid = threadIdx.x;

    __shared__ float sw_[NDEL];
    __shared__ int   sd_[NDEL];
    if (tid < NDEL) {
        sw_[tid] = w[b * NDEL + tid];
        sd_[tid] = delay[b * NDEL + tid];
    }
    __syncthreads();

    const float* vb = v + (size_t)bh * LSEQ * ND;
    float*       ob = out + (size_t)bh * LSEQ * ND;

    const int row = tid >> 4;
    const int col = (tid & 15) * 4;
    const int t   = bt * 16 + row;

    float4 acc = make_float4(0.f, 0.f, 0.f, 0.f);
    #pragma unroll
    for (int kk = 0; kk < NDEL; ++kk) {
        const int r = (t + sd_[kk]) & (LSEQ - 1);
        const float4 vv = *(const float4*)(vb + (size_t)r * ND + col);
        const float wv = sw_[kk];
        acc.x += wv * vv.x; acc.y += wv * vv.y;
        acc.z += wv * vv.z; acc.w += wv * vv.w;
    }
    f4nt val = {acc.x, acc.y, acc.z, acc.w};
    __builtin_nontemporal_store(val, (f4nt*)(ob + (size_t)t * ND + col));
}

// ---------------------------------------------------------------------------
extern "C" void kernel_launch(void* const* d_in, const int* in_sizes, int n_in,
                              void* d_out, int out_size, void* d_ws, size_t ws_size,
                              hipStream_t stream) {
    const float* q = (const float*)d_in[0];
    const float* k = (const float*)d_in[1];
    const float* v = (const float*)d_in[2];
    float* out = (float*)d_out;

    float2* Pc    = (float2*)((char*)d_ws + WS_P_OFF);
    float*  w     = (float*)((char*)d_ws + WS_W_OFF);
    int*    delay = (int*)((char*)d_ws + WS_DELAY_OFF);

    fft_corr<<<dim3(1024), dim3(256), 0, stream>>>(q, k, Pc);
    reduce_S<<<dim3(128), dim3(256), 0, stream>>>(Pc);
    ifft_topk<<<dim3(NB), dim3(256), 0, stream>>>(Pc, w, delay);  // part 0 = S
    gather_out<<<dim3(NB * NH * 128), dim3(256), 0, stream>>>(v, w, delay, out);
}